// Round 1
// baseline (11193.172 us; speedup 1.0000x reference)
//
#include <hip/hip_runtime.h>
#include <hip/hip_bf16.h>
#include <stdint.h>

#define N_NODES  131072
#define N_EDGES  2097152
#define N_GRAPHS 1024

// ---- monotonic float<->uint encoding for atomicMax-based scatter-max ----
// enc is order-preserving: f1 < f2  <=>  enc(f1) < enc(f2) (unsigned).
// Buffer initialized to enc(0.0f) = 0x80000000 so the final decoded value is
// max(0, max(messages)) == relu(where(isfinite(segment_max), ., 0)) exactly.
__device__ __forceinline__ unsigned enc_f32(float f) {
  unsigned b = __float_as_uint(f);
  return (b & 0x80000000u) ? ~b : (b | 0x80000000u);
}
__device__ __forceinline__ float dec_pos(unsigned u) {
  // valid because result is always >= enc(0.0)
  return __uint_as_float(u & 0x7fffffffu);
}

// ---- init workspace: agg buffers to enc(0), pool/cnt to 0 ----
__global__ void init_ws(uint4* __restrict__ h1, uint4* __restrict__ h2,
                        float* __restrict__ pool, float* __restrict__ cnt) {
  const int HN4 = N_NODES * 64 / 4;
  uint4 v = make_uint4(0x80000000u, 0x80000000u, 0x80000000u, 0x80000000u);
  int stride = gridDim.x * blockDim.x;
  for (int t = blockIdx.x * blockDim.x + threadIdx.x; t < HN4; t += stride) {
    h1[t] = v;
    h2[t] = v;
  }
  for (int t = blockIdx.x * blockDim.x + threadIdx.x; t < N_GRAPHS * 64; t += stride)
    pool[t] = 0.0f;
  for (int t = blockIdx.x * blockDim.x + threadIdx.x; t < N_GRAPHS; t += stride)
    cnt[t] = 0.0f;
}

// ---- conv1: m = [x[dst](16), x[src](16), ea(6)] -> relu(@w1+b1) @ w2 + b2 ----
// thread = edge. Weights indexed wave-uniformly -> s_load, SGPR operand in v_fma.
__global__ __launch_bounds__(256) void conv1(
    const float* __restrict__ x, const float* __restrict__ ea,
    const int* __restrict__ srcs, const int* __restrict__ dsts,
    const float* __restrict__ w1, const float* __restrict__ b1,
    const float* __restrict__ w2, const float* __restrict__ b2,
    unsigned* __restrict__ agg) {
  int e = blockIdx.x * 256 + threadIdx.x;
  int s = srcs[e], d = dsts[e];

  float m[38];
  {
    const float4* xd = (const float4*)(x + (size_t)d * 16);
    const float4* xs = (const float4*)(x + (size_t)s * 16);
#pragma unroll
    for (int i = 0; i < 4; i++) {
      float4 v = xd[i];
      m[4 * i + 0] = v.x; m[4 * i + 1] = v.y; m[4 * i + 2] = v.z; m[4 * i + 3] = v.w;
    }
#pragma unroll
    for (int i = 0; i < 4; i++) {
      float4 v = xs[i];
      m[16 + 4 * i + 0] = v.x; m[16 + 4 * i + 1] = v.y; m[16 + 4 * i + 2] = v.z; m[16 + 4 * i + 3] = v.w;
    }
    const float2* e2 = (const float2*)(ea + (size_t)e * 6);
#pragma unroll
    for (int i = 0; i < 3; i++) {
      float2 v = e2[i];
      m[32 + 2 * i] = v.x; m[33 + 2 * i] = v.y;
    }
  }

  float out[64];
#pragma unroll
  for (int o = 0; o < 64; o++) out[o] = b2[o];

#pragma unroll 1
  for (int jc = 0; jc < 4; ++jc) {  // hidden in chunks of 16 to bound code size
    float acc[16];
#pragma unroll
    for (int j = 0; j < 16; j++) acc[j] = b1[jc * 16 + j];
#pragma unroll
    for (int k = 0; k < 38; k++) {
#pragma unroll
      for (int j = 0; j < 16; j++)
        acc[j] = fmaf(m[k], w1[k * 64 + jc * 16 + j], acc[j]);
    }
#pragma unroll
    for (int j = 0; j < 16; j++) {
      float h = fmaxf(acc[j], 0.0f);
      const float* w2r = w2 + (jc * 16 + j) * 64;
#pragma unroll
      for (int o = 0; o < 64; o++) out[o] = fmaf(h, w2r[o], out[o]);
    }
  }

  unsigned* a = agg + (size_t)d * 64;
#pragma unroll
  for (int o = 0; o < 64; o++) atomicMax(a + o, enc_f32(out[o]));
}

// ---- conv2: m = [h1[dst](64), h1[src](64), ea(6)] ----
__global__ __launch_bounds__(256) void conv2(
    const unsigned* __restrict__ h1, const float* __restrict__ ea,
    const int* __restrict__ srcs, const int* __restrict__ dsts,
    const float* __restrict__ w1, const float* __restrict__ b1,
    const float* __restrict__ w2, const float* __restrict__ b2,
    unsigned* __restrict__ agg) {
  int e = blockIdx.x * 256 + threadIdx.x;
  int s = srcs[e], d = dsts[e];

  float acc[64];
#pragma unroll
  for (int j = 0; j < 64; j++) acc[j] = b1[j];

  const uint4* hd = (const uint4*)(h1 + (size_t)d * 64);
  const uint4* hs = (const uint4*)(h1 + (size_t)s * 64);

#pragma unroll 2
  for (int kk = 0; kk < 16; kk++) {  // k = 0..63 : h1[dst]
    uint4 u = hd[kk];
    float v0 = dec_pos(u.x), v1 = dec_pos(u.y), v2 = dec_pos(u.z), v3 = dec_pos(u.w);
    const float* wr = w1 + (kk * 4) * 64;
#pragma unroll
    for (int j = 0; j < 64; j++) acc[j] = fmaf(v0, wr[j], acc[j]);
#pragma unroll
    for (int j = 0; j < 64; j++) acc[j] = fmaf(v1, wr[64 + j], acc[j]);
#pragma unroll
    for (int j = 0; j < 64; j++) acc[j] = fmaf(v2, wr[128 + j], acc[j]);
#pragma unroll
    for (int j = 0; j < 64; j++) acc[j] = fmaf(v3, wr[192 + j], acc[j]);
  }
#pragma unroll 2
  for (int kk = 0; kk < 16; kk++) {  // k = 64..127 : h1[src]
    uint4 u = hs[kk];
    float v0 = dec_pos(u.x), v1 = dec_pos(u.y), v2 = dec_pos(u.z), v3 = dec_pos(u.w);
    const float* wr = w1 + (64 + kk * 4) * 64;
#pragma unroll
    for (int j = 0; j < 64; j++) acc[j] = fmaf(v0, wr[j], acc[j]);
#pragma unroll
    for (int j = 0; j < 64; j++) acc[j] = fmaf(v1, wr[64 + j], acc[j]);
#pragma unroll
    for (int j = 0; j < 64; j++) acc[j] = fmaf(v2, wr[128 + j], acc[j]);
#pragma unroll
    for (int j = 0; j < 64; j++) acc[j] = fmaf(v3, wr[192 + j], acc[j]);
  }
  {  // k = 128..133 : edge_attr
    const float2* e2 = (const float2*)(ea + (size_t)e * 6);
#pragma unroll
    for (int i = 0; i < 3; i++) {
      float2 v = e2[i];
      const float* wr = w1 + (128 + 2 * i) * 64;
#pragma unroll
      for (int j = 0; j < 64; j++) acc[j] = fmaf(v.x, wr[j], acc[j]);
#pragma unroll
      for (int j = 0; j < 64; j++) acc[j] = fmaf(v.y, wr[64 + j], acc[j]);
    }
  }

  float out[64];
#pragma unroll
  for (int o = 0; o < 64; o++) out[o] = b2[o];
#pragma unroll
  for (int j = 0; j < 64; j++) {
    float h = fmaxf(acc[j], 0.0f);
    const float* w2r = w2 + j * 64;
#pragma unroll
    for (int o = 0; o < 64; o++) out[o] = fmaf(h, w2r[o], out[o]);
  }

  unsigned* a = agg + (size_t)d * 64;
#pragma unroll
  for (int o = 0; o < 64; o++) atomicMax(a + o, enc_f32(out[o]));
}

// ---- mean pool: atomicAdd of decoded h2 into per-graph sums ----
__global__ __launch_bounds__(256) void pool_accum(
    const unsigned* __restrict__ h2, const int* __restrict__ batch,
    float* __restrict__ pool, float* __restrict__ cnt) {
  int t = blockIdx.x * 256 + threadIdx.x;  // t in [0, N*64)
  int n = t >> 6, o = t & 63;
  int b = batch[n];
  atomicAdd(pool + (size_t)b * 64 + o, dec_pos(h2[t]));
  if (o == 0) atomicAdd(cnt + b, 1.0f);
}

// ---- readout: z = relu(pooled @ wr1 + br1) @ wr2 + br2 ----
__global__ __launch_bounds__(64) void readout(
    const float* __restrict__ pool, const float* __restrict__ cnt,
    const float* __restrict__ wr1, const float* __restrict__ br1,
    const float* __restrict__ wr2, const float* __restrict__ br2,
    float* __restrict__ out) {
  int g = blockIdx.x;
  int j = threadIdx.x;  // 0..63
  __shared__ float p[64], t[64];
  float c = fmaxf(cnt[g], 1.0f);
  p[j] = pool[(size_t)g * 64 + j] / c;
  __syncthreads();
  float a = br1[j];
#pragma unroll 8
  for (int k = 0; k < 64; k++) a = fmaf(p[k], wr1[k * 64 + j], a);
  t[j] = fmaxf(a, 0.0f);
  __syncthreads();
  float z0 = br2[j], z1 = br2[64 + j];
#pragma unroll 8
  for (int k = 0; k < 64; k++) {
    float tk = t[k];
    z0 = fmaf(tk, wr2[k * 128 + j], z0);
    z1 = fmaf(tk, wr2[k * 128 + 64 + j], z1);
  }
  out[(size_t)g * 128 + j] = z0;
  out[(size_t)g * 128 + 64 + j] = z1;
}

extern "C" void kernel_launch(void* const* d_in, const int* in_sizes, int n_in,
                              void* d_out, int out_size, void* d_ws, size_t ws_size,
                              hipStream_t stream) {
  const float* x     = (const float*)d_in[0];
  const float* ea    = (const float*)d_in[1];
  const int*   ei    = (const int*)d_in[2];
  const int*   batch = (const int*)d_in[3];
  const float* w11 = (const float*)d_in[4];
  const float* b11 = (const float*)d_in[5];
  const float* w12 = (const float*)d_in[6];
  const float* b12 = (const float*)d_in[7];
  const float* w21 = (const float*)d_in[8];
  const float* b21 = (const float*)d_in[9];
  const float* w22 = (const float*)d_in[10];
  const float* b22 = (const float*)d_in[11];
  const float* wr1 = (const float*)d_in[12];
  const float* br1 = (const float*)d_in[13];
  const float* wr2 = (const float*)d_in[14];
  const float* br2 = (const float*)d_in[15];
  float* out = (float*)d_out;

  char* ws = (char*)d_ws;
  const size_t HBYTES = (size_t)N_NODES * 64 * 4;  // 33.55 MB
  unsigned* h1   = (unsigned*)(ws);
  unsigned* h2   = (unsigned*)(ws + HBYTES);
  float*    pool = (float*)(ws + 2 * HBYTES);
  float*    cnt  = (float*)(ws + 2 * HBYTES + (size_t)N_GRAPHS * 64 * 4);

  const int* src = ei;            // edge_index[0]
  const int* dst = ei + N_EDGES;  // edge_index[1]

  init_ws<<<4096, 256, 0, stream>>>((uint4*)h1, (uint4*)h2, pool, cnt);
  conv1<<<N_EDGES / 256, 256, 0, stream>>>(x, ea, src, dst, w11, b11, w12, b12, h1);
  conv2<<<N_EDGES / 256, 256, 0, stream>>>(h1, ea, src, dst, w21, b21, w22, b22, h2);
  pool_accum<<<N_NODES * 64 / 256, 256, 0, stream>>>(h2, batch, pool, cnt);
  readout<<<N_GRAPHS, 64, 0, stream>>>(pool, cnt, wr1, br1, wr2, br2, out);
}

// Round 2
// 3308.473 us; speedup vs baseline: 3.3832x; 3.3832x over previous
//
#include <hip/hip_runtime.h>
#include <stdint.h>

#define NN 131072
#define NE 2097152
#define NG 1024

// ---------------- CSR build ----------------

__global__ void init_zero(int* __restrict__ counts, int* __restrict__ fill,
                          int* __restrict__ bcnt) {
  int stride = gridDim.x * blockDim.x;
  for (int t = blockIdx.x * blockDim.x + threadIdx.x; t < NN; t += stride) {
    counts[t] = 0;
    fill[t] = 0;
  }
  for (int t = blockIdx.x * blockDim.x + threadIdx.x; t < NG; t += stride)
    bcnt[t] = 0;
}

__global__ __launch_bounds__(256) void count_dst(const int* __restrict__ dst,
                                                 int* __restrict__ counts) {
  int e = blockIdx.x * 256 + threadIdx.x;
  atomicAdd(&counts[dst[e]], 1);
}

__global__ __launch_bounds__(256) void count_batch(const int* __restrict__ batch,
                                                   int* __restrict__ bcnt) {
  int n = blockIdx.x * 256 + threadIdx.x;
  atomicAdd(&bcnt[batch[n]], 1);
}

// scanA: per-block exclusive scan of 256 counts -> rp, block totals -> bsum
__global__ __launch_bounds__(256) void scanA(const int* __restrict__ counts,
                                             int* __restrict__ rp,
                                             int* __restrict__ bsum) {
  __shared__ int sm[256];
  int t = threadIdx.x;
  int g = blockIdx.x * 256 + t;
  int v = counts[g];
  sm[t] = v;
  __syncthreads();
  for (int off = 1; off < 256; off <<= 1) {
    int a = (t >= off) ? sm[t - off] : 0;
    __syncthreads();
    sm[t] += a;
    __syncthreads();
  }
  rp[g] = sm[t] - v;  // exclusive
  if (t == 255) bsum[blockIdx.x] = sm[255];
}

// scanB: exclusive scan of the 512 block sums (single block)
__global__ __launch_bounds__(512) void scanB(int* __restrict__ bsum) {
  __shared__ int sm[512];
  int t = threadIdx.x;
  int v = bsum[t];
  sm[t] = v;
  __syncthreads();
  for (int off = 1; off < 512; off <<= 1) {
    int a = (t >= off) ? sm[t - off] : 0;
    __syncthreads();
    sm[t] += a;
    __syncthreads();
  }
  bsum[t] = sm[t] - v;
}

__global__ __launch_bounds__(256) void scanC(int* __restrict__ rp,
                                             const int* __restrict__ bsum) {
  int g = blockIdx.x * 256 + threadIdx.x;
  rp[g] += bsum[blockIdx.x];
  if (g == 0) rp[NN] = NE;
}

// batch scan: 1024 elements, one block
__global__ __launch_bounds__(1024) void scan_batch(const int* __restrict__ bcnt,
                                                   int* __restrict__ bp) {
  __shared__ int sm[1024];
  int t = threadIdx.x;
  int v = bcnt[t];
  sm[t] = v;
  __syncthreads();
  for (int off = 1; off < 1024; off <<= 1) {
    int a = (t >= off) ? sm[t - off] : 0;
    __syncthreads();
    sm[t] += a;
    __syncthreads();
  }
  bp[t] = sm[t] - v;
  if (t == 1023) bp[NG] = NN;
}

__global__ __launch_bounds__(256) void scatter(const int* __restrict__ src,
                                               const int* __restrict__ dst,
                                               const int* __restrict__ rp,
                                               int* __restrict__ fill,
                                               int* __restrict__ eperm,
                                               int* __restrict__ sp) {
  int e = blockIdx.x * 256 + threadIdx.x;
  int d = dst[e];
  int p = rp[d] + atomicAdd(&fill[d], 1);
  eperm[p] = e;
  sp[p] = src[e];
}

// ---------------- conv1: thread per node ----------------
// m = [x[n](16), x[src](16), ea(6)] -> relu(@w1+b1) @ w2 + b2, max over edges.
// Weights indexed with compile-time-constant offsets -> wave-uniform s_load.
__global__ __launch_bounds__(256) void conv1(
    const float* __restrict__ x, const float* __restrict__ ea,
    const int* __restrict__ sp, const int* __restrict__ eperm,
    const int* __restrict__ rp,
    const float* __restrict__ w1, const float* __restrict__ b1,
    const float* __restrict__ w2, const float* __restrict__ b2,
    float* __restrict__ h1) {
  int n = blockIdx.x * 256 + threadIdx.x;

  // dst-half of layer1 is loop-invariant: precompute once per node.
  float accD[64];
  {
    float xd[16];
    const float4* x4 = (const float4*)(x + (size_t)n * 16);
#pragma unroll
    for (int i = 0; i < 4; i++) {
      float4 v = x4[i];
      xd[4 * i] = v.x; xd[4 * i + 1] = v.y; xd[4 * i + 2] = v.z; xd[4 * i + 3] = v.w;
    }
#pragma unroll
    for (int j = 0; j < 64; j++) accD[j] = b1[j];
#pragma unroll
    for (int k = 0; k < 16; k++) {
#pragma unroll
      for (int j = 0; j < 64; j++) accD[j] = fmaf(xd[k], w1[k * 64 + j], accD[j]);
    }
  }

  float mx[64];
#pragma unroll
  for (int o = 0; o < 64; o++) mx[o] = 0.0f;  // init 0 == relu(empty) semantics

  int lo = rp[n], hi = rp[n + 1];
  for (int i = lo; i < hi; ++i) {
    int s = sp[i];
    int e = eperm[i];

    float acc[64];
#pragma unroll
    for (int j = 0; j < 64; j++) acc[j] = accD[j];

    const float4* xs4 = (const float4*)(x + (size_t)s * 16);
#pragma unroll
    for (int kk = 0; kk < 4; kk++) {
      float4 v = xs4[kk];
      const float* wr = w1 + (16 + kk * 4) * 64;
#pragma unroll
      for (int j = 0; j < 64; j++) acc[j] = fmaf(v.x, wr[j], acc[j]);
#pragma unroll
      for (int j = 0; j < 64; j++) acc[j] = fmaf(v.y, wr[64 + j], acc[j]);
#pragma unroll
      for (int j = 0; j < 64; j++) acc[j] = fmaf(v.z, wr[128 + j], acc[j]);
#pragma unroll
      for (int j = 0; j < 64; j++) acc[j] = fmaf(v.w, wr[192 + j], acc[j]);
    }
    const float2* e2 = (const float2*)(ea + (size_t)e * 6);
#pragma unroll
    for (int t = 0; t < 3; t++) {
      float2 v = e2[t];
      const float* wr = w1 + (32 + 2 * t) * 64;
#pragma unroll
      for (int j = 0; j < 64; j++) acc[j] = fmaf(v.x, wr[j], acc[j]);
#pragma unroll
      for (int j = 0; j < 64; j++) acc[j] = fmaf(v.y, wr[64 + j], acc[j]);
    }

    // layer2 chunked over 16 output channels to bound live registers;
    // relu(acc[j]) recomputed per chunk (cheap) so acc stays the only big array.
#pragma unroll 1
    for (int oc = 0; oc < 4; ++oc) {
      float out[16];
#pragma unroll
      for (int o = 0; o < 16; o++) out[o] = b2[oc * 16 + o];
#pragma unroll
      for (int j = 0; j < 64; j++) {
        float h = fmaxf(acc[j], 0.0f);
        const float* w2r = w2 + j * 64 + oc * 16;
#pragma unroll
        for (int o = 0; o < 16; o++) out[o] = fmaf(h, w2r[o], out[o]);
      }
#pragma unroll
      for (int o = 0; o < 16; o++)
        mx[oc * 16 + o] = fmaxf(mx[oc * 16 + o], out[o]);
    }
  }

  float4* h4 = (float4*)(h1 + (size_t)n * 64);
#pragma unroll
  for (int o = 0; o < 16; o++)
    h4[o] = make_float4(mx[4 * o], mx[4 * o + 1], mx[4 * o + 2], mx[4 * o + 3]);
}

// ---------------- conv2: thread per node ----------------
__global__ __launch_bounds__(256) void conv2(
    const float* __restrict__ h1, const float* __restrict__ ea,
    const int* __restrict__ sp, const int* __restrict__ eperm,
    const int* __restrict__ rp,
    const float* __restrict__ w1, const float* __restrict__ b1,
    const float* __restrict__ w2, const float* __restrict__ b2,
    float* __restrict__ h2) {
  int n = blockIdx.x * 256 + threadIdx.x;

  float accD[64];
  {
#pragma unroll
    for (int j = 0; j < 64; j++) accD[j] = b1[j];
    const float4* hd4 = (const float4*)(h1 + (size_t)n * 64);
#pragma unroll
    for (int kk = 0; kk < 16; kk++) {
      float4 v = hd4[kk];
      const float* wr = w1 + (kk * 4) * 64;
#pragma unroll
      for (int j = 0; j < 64; j++) accD[j] = fmaf(v.x, wr[j], accD[j]);
#pragma unroll
      for (int j = 0; j < 64; j++) accD[j] = fmaf(v.y, wr[64 + j], accD[j]);
#pragma unroll
      for (int j = 0; j < 64; j++) accD[j] = fmaf(v.z, wr[128 + j], accD[j]);
#pragma unroll
      for (int j = 0; j < 64; j++) accD[j] = fmaf(v.w, wr[192 + j], accD[j]);
    }
  }

  float mx[64];
#pragma unroll
  for (int o = 0; o < 64; o++) mx[o] = 0.0f;

  int lo = rp[n], hi = rp[n + 1];
  for (int i = lo; i < hi; ++i) {
    int s = sp[i];
    int e = eperm[i];

    float acc[64];
#pragma unroll
    for (int j = 0; j < 64; j++) acc[j] = accD[j];

    const float4* hs4 = (const float4*)(h1 + (size_t)s * 64);
#pragma unroll 4
    for (int kk = 0; kk < 16; kk++) {  // src half, chunk of 4 k's at a time
      float4 v = hs4[kk];
      const float* wr = w1 + (64 + kk * 4) * 64;
#pragma unroll
      for (int j = 0; j < 64; j++) acc[j] = fmaf(v.x, wr[j], acc[j]);
#pragma unroll
      for (int j = 0; j < 64; j++) acc[j] = fmaf(v.y, wr[64 + j], acc[j]);
#pragma unroll
      for (int j = 0; j < 64; j++) acc[j] = fmaf(v.z, wr[128 + j], acc[j]);
#pragma unroll
      for (int j = 0; j < 64; j++) acc[j] = fmaf(v.w, wr[192 + j], acc[j]);
    }
    const float2* e2 = (const float2*)(ea + (size_t)e * 6);
#pragma unroll
    for (int t = 0; t < 3; t++) {
      float2 v = e2[t];
      const float* wr = w1 + (128 + 2 * t) * 64;
#pragma unroll
      for (int j = 0; j < 64; j++) acc[j] = fmaf(v.x, wr[j], acc[j]);
#pragma unroll
      for (int j = 0; j < 64; j++) acc[j] = fmaf(v.y, wr[64 + j], acc[j]);
    }

#pragma unroll 1
    for (int oc = 0; oc < 4; ++oc) {
      float out[16];
#pragma unroll
      for (int o = 0; o < 16; o++) out[o] = b2[oc * 16 + o];
#pragma unroll
      for (int j = 0; j < 64; j++) {
        float h = fmaxf(acc[j], 0.0f);
        const float* w2r = w2 + j * 64 + oc * 16;
#pragma unroll
        for (int o = 0; o < 16; o++) out[o] = fmaf(h, w2r[o], out[o]);
      }
#pragma unroll
      for (int o = 0; o < 16; o++)
        mx[oc * 16 + o] = fmaxf(mx[oc * 16 + o], out[o]);
    }
  }

  float4* h4 = (float4*)(h2 + (size_t)n * 64);
#pragma unroll
  for (int o = 0; o < 16; o++)
    h4[o] = make_float4(mx[4 * o], mx[4 * o + 1], mx[4 * o + 2], mx[4 * o + 3]);
}

// ---------------- fused mean-pool + readout: block per graph ----------------
__global__ __launch_bounds__(64) void readout(
    const float* __restrict__ h2, const int* __restrict__ bp,
    const float* __restrict__ wr1, const float* __restrict__ br1,
    const float* __restrict__ wr2, const float* __restrict__ br2,
    float* __restrict__ out) {
  int g = blockIdx.x;
  int j = threadIdx.x;  // 0..63
  int lo = bp[g], hi = bp[g + 1];
  float s = 0.0f;
  for (int n = lo; n < hi; ++n) s += h2[(size_t)n * 64 + j];  // coalesced
  __shared__ float p[64], t[64];
  float c = fmaxf((float)(hi - lo), 1.0f);
  p[j] = s / c;
  __syncthreads();
  float a = br1[j];
#pragma unroll 8
  for (int k = 0; k < 64; k++) a = fmaf(p[k], wr1[k * 64 + j], a);
  t[j] = fmaxf(a, 0.0f);
  __syncthreads();
  float z0 = br2[j], z1 = br2[64 + j];
#pragma unroll 8
  for (int k = 0; k < 64; k++) {
    float tk = t[k];
    z0 = fmaf(tk, wr2[k * 128 + j], z0);
    z1 = fmaf(tk, wr2[k * 128 + 64 + j], z1);
  }
  out[(size_t)g * 128 + j] = z0;
  out[(size_t)g * 128 + 64 + j] = z1;
}

// ---------------- launch ----------------
extern "C" void kernel_launch(void* const* d_in, const int* in_sizes, int n_in,
                              void* d_out, int out_size, void* d_ws, size_t ws_size,
                              hipStream_t stream) {
  const float* x     = (const float*)d_in[0];
  const float* ea    = (const float*)d_in[1];
  const int*   ei    = (const int*)d_in[2];
  const int*   batch = (const int*)d_in[3];
  const float* w11 = (const float*)d_in[4];
  const float* b11 = (const float*)d_in[5];
  const float* w12 = (const float*)d_in[6];
  const float* b12 = (const float*)d_in[7];
  const float* w21 = (const float*)d_in[8];
  const float* b21 = (const float*)d_in[9];
  const float* w22 = (const float*)d_in[10];
  const float* b22 = (const float*)d_in[11];
  const float* wr1 = (const float*)d_in[12];
  const float* br1 = (const float*)d_in[13];
  const float* wr2 = (const float*)d_in[14];
  const float* br2 = (const float*)d_in[15];
  float* out = (float*)d_out;

  const int* src = ei;       // edge_index[0]
  const int* dst = ei + NE;  // edge_index[1]

  char* ws = (char*)d_ws;
  size_t off = 0;
  auto alloc = [&](size_t bytes) {
    char* p = ws + off;
    off = (off + bytes + 255) & ~(size_t)255;
    return p;
  };
  float* h1    = (float*)alloc((size_t)NN * 64 * 4);  // 33.55 MB
  float* h2    = (float*)alloc((size_t)NN * 64 * 4);  // 33.55 MB
  int*   sp    = (int*)alloc((size_t)NE * 4);         // 8.39 MB
  int*   eperm = (int*)alloc((size_t)NE * 4);         // 8.39 MB
  int*   rp    = (int*)alloc((size_t)(NN + 1) * 4);
  int*   counts= (int*)alloc((size_t)NN * 4);
  int*   fill  = (int*)alloc((size_t)NN * 4);
  int*   bcnt  = (int*)alloc((size_t)NG * 4);
  int*   bp    = (int*)alloc((size_t)(NG + 1) * 4);
  int*   bsum  = (int*)alloc(512 * 4);

  init_zero<<<512, 256, 0, stream>>>(counts, fill, bcnt);
  count_dst<<<NE / 256, 256, 0, stream>>>(dst, counts);
  count_batch<<<NN / 256, 256, 0, stream>>>(batch, bcnt);
  scanA<<<NN / 256, 256, 0, stream>>>(counts, rp, bsum);
  scanB<<<1, 512, 0, stream>>>(bsum);
  scanC<<<NN / 256, 256, 0, stream>>>(rp, bsum);
  scan_batch<<<1, 1024, 0, stream>>>(bcnt, bp);
  scatter<<<NE / 256, 256, 0, stream>>>(src, dst, rp, fill, eperm, sp);
  conv1<<<NN / 256, 256, 0, stream>>>(x, ea, sp, eperm, rp, w11, b11, w12, b12, h1);
  conv2<<<NN / 256, 256, 0, stream>>>(h1, ea, sp, eperm, rp, w21, b21, w22, b22, h2);
  readout<<<NG, 64, 0, stream>>>(h2, bp, wr1, br1, wr2, br2, out);
}

// Round 3
// 1543.739 us; speedup vs baseline: 7.2507x; 2.1432x over previous
//
#include <hip/hip_runtime.h>
#include <stdint.h>

#define NN 131072
#define NE 2097152
#define NG 1024

// monotone float<->uint encoding: f1 < f2  <=>  enc(f1) < enc(f2) (unsigned).
// h-buffers live in encoded space, initialized to enc(0.0)=0x80000000 so the
// decoded value is relu(segment_max) with empty segments -> 0 (matches ref).
__device__ __forceinline__ unsigned enc_f32(float f) {
  unsigned b = __float_as_uint(f);
  return (b & 0x80000000u) ? ~b : (b | 0x80000000u);
}
__device__ __forceinline__ float dec_pos(unsigned u) {
  return __uint_as_float(u & 0x7fffffffu);
}

// ---------------- init ----------------
__global__ void init_ws(uint4* __restrict__ h1, uint4* __restrict__ h2,
                        int* __restrict__ counts, int* __restrict__ fill,
                        int* __restrict__ bcnt) {
  const int HN4 = NN * 64 / 4;
  uint4 v = make_uint4(0x80000000u, 0x80000000u, 0x80000000u, 0x80000000u);
  int stride = gridDim.x * blockDim.x;
  for (int t = blockIdx.x * blockDim.x + threadIdx.x; t < HN4; t += stride) {
    h1[t] = v;
    h2[t] = v;
  }
  for (int t = blockIdx.x * blockDim.x + threadIdx.x; t < NN; t += stride) {
    counts[t] = 0;
    fill[t] = 0;
  }
  for (int t = blockIdx.x * blockDim.x + threadIdx.x; t < NG; t += stride)
    bcnt[t] = 0;
}

// ---------------- CSR build ----------------
__global__ __launch_bounds__(256) void count_dst(const int* __restrict__ dst,
                                                 int* __restrict__ counts) {
  int e = blockIdx.x * 256 + threadIdx.x;
  atomicAdd(&counts[dst[e]], 1);
}

__global__ __launch_bounds__(256) void count_batch(const int* __restrict__ batch,
                                                   int* __restrict__ bcnt) {
  int n = blockIdx.x * 256 + threadIdx.x;
  atomicAdd(&bcnt[batch[n]], 1);
}

__global__ __launch_bounds__(256) void scanA(const int* __restrict__ counts,
                                             int* __restrict__ rp,
                                             int* __restrict__ bsum) {
  __shared__ int sm[256];
  int t = threadIdx.x;
  int g = blockIdx.x * 256 + t;
  int v = counts[g];
  sm[t] = v;
  __syncthreads();
  for (int off = 1; off < 256; off <<= 1) {
    int a = (t >= off) ? sm[t - off] : 0;
    __syncthreads();
    sm[t] += a;
    __syncthreads();
  }
  rp[g] = sm[t] - v;
  if (t == 255) bsum[blockIdx.x] = sm[255];
}

__global__ __launch_bounds__(512) void scanB(int* __restrict__ bsum) {
  __shared__ int sm[512];
  int t = threadIdx.x;
  int v = bsum[t];
  sm[t] = v;
  __syncthreads();
  for (int off = 1; off < 512; off <<= 1) {
    int a = (t >= off) ? sm[t - off] : 0;
    __syncthreads();
    sm[t] += a;
    __syncthreads();
  }
  bsum[t] = sm[t] - v;
}

__global__ __launch_bounds__(256) void scanC(int* __restrict__ rp,
                                             const int* __restrict__ bsum) {
  int g = blockIdx.x * 256 + threadIdx.x;
  rp[g] += bsum[blockIdx.x];
  if (g == 0) rp[NN] = NE;
}

__global__ __launch_bounds__(1024) void scan_batch(const int* __restrict__ bcnt,
                                                   int* __restrict__ bp) {
  __shared__ int sm[1024];
  int t = threadIdx.x;
  int v = bcnt[t];
  sm[t] = v;
  __syncthreads();
  for (int off = 1; off < 1024; off <<= 1) {
    int a = (t >= off) ? sm[t - off] : 0;
    __syncthreads();
    sm[t] += a;
    __syncthreads();
  }
  bp[t] = sm[t] - v;
  if (t == 1023) bp[NG] = NN;
}

// scatter edges into CSR order; optionally pre-permute edge_attr for
// coalesced reads in the conv kernels.
__global__ __launch_bounds__(256) void scatter(
    const int* __restrict__ src, const int* __restrict__ dst,
    const float* __restrict__ ea, const int* __restrict__ rp,
    int* __restrict__ fill, int* __restrict__ eperm, int* __restrict__ sp,
    int* __restrict__ dst_p, float* __restrict__ ea_p, int use_eap) {
  int e = blockIdx.x * 256 + threadIdx.x;
  int d = dst[e];
  int p = rp[d] + atomicAdd(&fill[d], 1);
  eperm[p] = e;
  sp[p] = src[e];
  dst_p[p] = d;
  if (use_eap) {
    const float2* s2 = (const float2*)(ea + (size_t)e * 6);
    float2 a = s2[0], b = s2[1], c = s2[2];
    float2* d2 = (float2*)(ea_p + (size_t)p * 6);
    d2[0] = a; d2[1] = b; d2[2] = c;
  }
}

// ---------------- node-level GEMMs: P = H@Wd + b1, Q = H@Ws ----------------
// blocks 0..511 compute P, 512..1023 compute Q -> weight base is wave-uniform.
__global__ __launch_bounds__(256) void nodePQ1(
    const float* __restrict__ x, const float* __restrict__ w1,
    const float* __restrict__ b1, float* __restrict__ P, float* __restrict__ Q) {
  int half = blockIdx.x >> 9;
  int n = (blockIdx.x & 511) * 256 + threadIdx.x;
  const float* w = w1 + half * 16 * 64;
  float acc[64];
#pragma unroll
  for (int j = 0; j < 64; j++) acc[j] = half ? 0.0f : b1[j];
  const float4* x4 = (const float4*)(x + (size_t)n * 16);
#pragma unroll
  for (int kk = 0; kk < 4; kk++) {
    float4 v = x4[kk];
    const float* wr = w + (kk * 4) * 64;
#pragma unroll
    for (int j = 0; j < 64; j++) acc[j] = fmaf(v.x, wr[j], acc[j]);
#pragma unroll
    for (int j = 0; j < 64; j++) acc[j] = fmaf(v.y, wr[64 + j], acc[j]);
#pragma unroll
    for (int j = 0; j < 64; j++) acc[j] = fmaf(v.z, wr[128 + j], acc[j]);
#pragma unroll
    for (int j = 0; j < 64; j++) acc[j] = fmaf(v.w, wr[192 + j], acc[j]);
  }
  float4* o = (float4*)((half ? Q : P) + (size_t)n * 64);
#pragma unroll
  for (int j = 0; j < 16; j++)
    o[j] = make_float4(acc[4 * j], acc[4 * j + 1], acc[4 * j + 2], acc[4 * j + 3]);
}

__global__ __launch_bounds__(256) void nodePQ2(
    const unsigned* __restrict__ h1, const float* __restrict__ w1,
    const float* __restrict__ b1, float* __restrict__ P, float* __restrict__ Q) {
  int half = blockIdx.x >> 9;
  int n = (blockIdx.x & 511) * 256 + threadIdx.x;
  const float* w = w1 + half * 64 * 64;
  float acc[64];
#pragma unroll
  for (int j = 0; j < 64; j++) acc[j] = half ? 0.0f : b1[j];
  const uint4* h4 = (const uint4*)(h1 + (size_t)n * 64);
#pragma unroll 4
  for (int kk = 0; kk < 16; kk++) {
    uint4 u = h4[kk];
    float v0 = dec_pos(u.x), v1 = dec_pos(u.y), v2 = dec_pos(u.z), v3 = dec_pos(u.w);
    const float* wr = w + (kk * 4) * 64;
#pragma unroll
    for (int j = 0; j < 64; j++) acc[j] = fmaf(v0, wr[j], acc[j]);
#pragma unroll
    for (int j = 0; j < 64; j++) acc[j] = fmaf(v1, wr[64 + j], acc[j]);
#pragma unroll
    for (int j = 0; j < 64; j++) acc[j] = fmaf(v2, wr[128 + j], acc[j]);
#pragma unroll
    for (int j = 0; j < 64; j++) acc[j] = fmaf(v3, wr[192 + j], acc[j]);
  }
  float4* o = (float4*)((half ? Q : P) + (size_t)n * 64);
#pragma unroll
  for (int j = 0; j < 16; j++)
    o[j] = make_float4(acc[4 * j], acc[4 * j + 1], acc[4 * j + 2], acc[4 * j + 3]);
}

// ---------------- edge kernel: thread per CSR slot ----------------
// h = relu(P[dst] + Q[src] + ea@W1c); out = h@W2 + b2; segmented in-wave
// max-scan over the dst-sorted slots; tail lane stores (plain if the segment
// is wave-contained, else encoded atomicMax).
template <bool EAP>
__global__ __launch_bounds__(256) void edge_mlp(
    const float* __restrict__ P, const float* __restrict__ Q,
    const float* __restrict__ ea_p, const float* __restrict__ ea,
    const int* __restrict__ eperm, const int* __restrict__ sp,
    const int* __restrict__ dst_p, const int* __restrict__ rp,
    const float* __restrict__ w1c, const float* __restrict__ w2,
    const float* __restrict__ b2, unsigned* __restrict__ hout) {
  int g = blockIdx.x * 256 + threadIdx.x;
  int lane = threadIdx.x & 63;
  int wavebase = g - lane;
  int d = dst_p[g], s = sp[g];
  int seg_lo = rp[d], seg_hi = rp[d + 1];

  float h[64];
  {
    const float4* Pd = (const float4*)(P + (size_t)d * 64);
    const float4* Qs = (const float4*)(Q + (size_t)s * 64);
#pragma unroll
    for (int kk = 0; kk < 16; kk++) {
      float4 a = Pd[kk];
      float4 b = Qs[kk];
      h[4 * kk] = a.x + b.x;
      h[4 * kk + 1] = a.y + b.y;
      h[4 * kk + 2] = a.z + b.z;
      h[4 * kk + 3] = a.w + b.w;
    }
  }
  {
    float2 ev[3];
    if (EAP) {
      const float2* q = (const float2*)(ea_p + (size_t)g * 6);
      ev[0] = q[0]; ev[1] = q[1]; ev[2] = q[2];
    } else {
      int e = eperm[g];
      const float2* q = (const float2*)(ea + (size_t)e * 6);
      ev[0] = q[0]; ev[1] = q[1]; ev[2] = q[2];
    }
#pragma unroll
    for (int t = 0; t < 3; t++) {
      const float* wr = w1c + (2 * t) * 64;
#pragma unroll
      for (int j = 0; j < 64; j++) h[j] = fmaf(ev[t].x, wr[j], h[j]);
#pragma unroll
      for (int j = 0; j < 64; j++) h[j] = fmaf(ev[t].y, wr[64 + j], h[j]);
    }
  }
#pragma unroll
  for (int j = 0; j < 64; j++) h[j] = fmaxf(h[j], 0.0f);

  int headlane = seg_lo - wavebase;
  if (headlane < 0) headlane = 0;
  bool tail = (g == seg_hi - 1) || (lane == 63);
  bool whole = (seg_lo >= wavebase) && (seg_hi <= wavebase + 64);
  unsigned* arow = hout + (size_t)d * 64;

#pragma unroll 1
  for (int oc = 0; oc < 4; ++oc) {
    float out[16];
#pragma unroll
    for (int o = 0; o < 16; o++) out[o] = b2[oc * 16 + o];
#pragma unroll
    for (int j = 0; j < 64; j++) {
      float hj = h[j];
      const float* w2r = w2 + j * 64 + oc * 16;
#pragma unroll
      for (int o = 0; o < 16; o++) out[o] = fmaf(hj, w2r[o], out[o]);
    }
    // segmented inclusive max-scan (segments contiguous in lane order)
#pragma unroll
    for (int o = 0; o < 16; o++) {
      float v = out[o];
#pragma unroll
      for (int off = 1; off < 64; off <<= 1) {
        float u = __shfl_up(v, off);
        v = (lane - off >= headlane) ? fmaxf(v, u) : v;
      }
      out[o] = v;
    }
    if (tail) {
      if (whole) {
#pragma unroll
        for (int o = 0; o < 16; o++)
          arow[oc * 16 + o] = enc_f32(fmaxf(out[o], 0.0f));
      } else {
#pragma unroll
        for (int o = 0; o < 16; o++)
          atomicMax(arow + oc * 16 + o, enc_f32(out[o]));
      }
    }
  }
}

// ---------------- fused mean-pool + readout ----------------
__global__ __launch_bounds__(64) void readout(
    const unsigned* __restrict__ h2, const int* __restrict__ bp,
    const float* __restrict__ wr1, const float* __restrict__ br1,
    const float* __restrict__ wr2, const float* __restrict__ br2,
    float* __restrict__ out) {
  int g = blockIdx.x;
  int j = threadIdx.x;
  int lo = bp[g], hi = bp[g + 1];
  float s = 0.0f;
  for (int n = lo; n < hi; ++n) s += dec_pos(h2[(size_t)n * 64 + j]);
  __shared__ float p[64], t[64];
  float c = fmaxf((float)(hi - lo), 1.0f);
  p[j] = s / c;
  __syncthreads();
  float a = br1[j];
#pragma unroll 8
  for (int k = 0; k < 64; k++) a = fmaf(p[k], wr1[k * 64 + j], a);
  t[j] = fmaxf(a, 0.0f);
  __syncthreads();
  float z0 = br2[j], z1 = br2[64 + j];
#pragma unroll 8
  for (int k = 0; k < 64; k++) {
    float tk = t[k];
    z0 = fmaf(tk, wr2[k * 128 + j], z0);
    z1 = fmaf(tk, wr2[k * 128 + 64 + j], z1);
  }
  out[(size_t)g * 128 + j] = z0;
  out[(size_t)g * 128 + 64 + j] = z1;
}

// ---------------- launch ----------------
extern "C" void kernel_launch(void* const* d_in, const int* in_sizes, int n_in,
                              void* d_out, int out_size, void* d_ws, size_t ws_size,
                              hipStream_t stream) {
  const float* x     = (const float*)d_in[0];
  const float* ea    = (const float*)d_in[1];
  const int*   ei    = (const int*)d_in[2];
  const int*   batch = (const int*)d_in[3];
  const float* w11 = (const float*)d_in[4];
  const float* b11 = (const float*)d_in[5];
  const float* w12 = (const float*)d_in[6];
  const float* b12 = (const float*)d_in[7];
  const float* w21 = (const float*)d_in[8];
  const float* b21 = (const float*)d_in[9];
  const float* w22 = (const float*)d_in[10];
  const float* b22 = (const float*)d_in[11];
  const float* wr1 = (const float*)d_in[12];
  const float* br1 = (const float*)d_in[13];
  const float* wr2 = (const float*)d_in[14];
  const float* br2 = (const float*)d_in[15];
  float* out = (float*)d_out;

  const int* src = ei;
  const int* dst = ei + NE;

  char* ws = (char*)d_ws;
  size_t off = 0;
  auto alloc = [&](size_t bytes) {
    char* p = ws + off;
    off = (off + bytes + 255) & ~(size_t)255;
    return p;
  };
  unsigned* h1   = (unsigned*)alloc((size_t)NN * 64 * 4);  // 33.5 MB (encoded)
  unsigned* h2   = (unsigned*)alloc((size_t)NN * 64 * 4);  // 33.5 MB (encoded)
  float*    Pbuf = (float*)alloc((size_t)NN * 64 * 4);     // 33.5 MB
  float*    Qbuf = (float*)alloc((size_t)NN * 64 * 4);     // 33.5 MB
  int*   sp    = (int*)alloc((size_t)NE * 4);
  int*   eperm = (int*)alloc((size_t)NE * 4);
  int*   dst_p = (int*)alloc((size_t)NE * 4);
  int*   rp    = (int*)alloc((size_t)(NN + 1) * 4);
  int*   counts= (int*)alloc((size_t)NN * 4);
  int*   fill  = (int*)alloc((size_t)NN * 4);
  int*   bcnt  = (int*)alloc((size_t)NG * 4);
  int*   bp    = (int*)alloc((size_t)(NG + 1) * 4);
  int*   bsum  = (int*)alloc(512 * 4);
  float* ea_p  = (float*)alloc((size_t)NE * 6 * 4);        // 50.3 MB (optional)
  int use_eap = (off <= ws_size) ? 1 : 0;                  // fallback if ws too small

  init_ws<<<1024, 256, 0, stream>>>((uint4*)h1, (uint4*)h2, counts, fill, bcnt);
  count_dst<<<NE / 256, 256, 0, stream>>>(dst, counts);
  count_batch<<<NN / 256, 256, 0, stream>>>(batch, bcnt);
  scanA<<<NN / 256, 256, 0, stream>>>(counts, rp, bsum);
  scanB<<<1, 512, 0, stream>>>(bsum);
  scanC<<<NN / 256, 256, 0, stream>>>(rp, bsum);
  scan_batch<<<1, 1024, 0, stream>>>(bcnt, bp);
  scatter<<<NE / 256, 256, 0, stream>>>(src, dst, ea, rp, fill, eperm, sp,
                                        dst_p, ea_p, use_eap);

  nodePQ1<<<1024, 256, 0, stream>>>(x, w11, b11, Pbuf, Qbuf);
  if (use_eap)
    edge_mlp<true><<<NE / 256, 256, 0, stream>>>(Pbuf, Qbuf, ea_p, ea, eperm, sp,
                                                 dst_p, rp, w11 + 32 * 64, w12, b12, h1);
  else
    edge_mlp<false><<<NE / 256, 256, 0, stream>>>(Pbuf, Qbuf, ea_p, ea, eperm, sp,
                                                  dst_p, rp, w11 + 32 * 64, w12, b12, h1);

  nodePQ2<<<1024, 256, 0, stream>>>(h1, w21, b21, Pbuf, Qbuf);
  if (use_eap)
    edge_mlp<true><<<NE / 256, 256, 0, stream>>>(Pbuf, Qbuf, ea_p, ea, eperm, sp,
                                                 dst_p, rp, w21 + 128 * 64, w22, b22, h2);
  else
    edge_mlp<false><<<NE / 256, 256, 0, stream>>>(Pbuf, Qbuf, ea_p, ea, eperm, sp,
                                                  dst_p, rp, w21 + 128 * 64, w22, b22, h2);

  readout<<<NG, 64, 0, stream>>>(h2, bp, wr1, br1, wr2, br2, out);
}

// Round 4
// 1285.688 us; speedup vs baseline: 8.7060x; 1.2007x over previous
//
#include <hip/hip_runtime.h>
#include <stdint.h>

#define NN 131072
#define NE 2097152
#define NG 1024

// monotone float<->uint encoding: f1 < f2  <=>  enc(f1) < enc(f2) (unsigned).
// h-buffers live in encoded space, initialized to enc(0.0)=0x80000000 so the
// decoded value is relu(segment_max) with empty segments -> 0 (matches ref).
__device__ __forceinline__ unsigned enc_f32(float f) {
  unsigned b = __float_as_uint(f);
  return (b & 0x80000000u) ? ~b : (b | 0x80000000u);
}
__device__ __forceinline__ float dec_pos(unsigned u) {
  return __uint_as_float(u & 0x7fffffffu);
}

// ---------------- init ----------------
__global__ void init_ws(uint4* __restrict__ h1, uint4* __restrict__ h2,
                        int* __restrict__ counts, int* __restrict__ fill,
                        int* __restrict__ bcnt) {
  const int HN4 = NN * 64 / 4;
  uint4 v = make_uint4(0x80000000u, 0x80000000u, 0x80000000u, 0x80000000u);
  int stride = gridDim.x * blockDim.x;
  for (int t = blockIdx.x * blockDim.x + threadIdx.x; t < HN4; t += stride) {
    h1[t] = v;
    h2[t] = v;
  }
  for (int t = blockIdx.x * blockDim.x + threadIdx.x; t < NN; t += stride) {
    counts[t] = 0;
    fill[t] = 0;
  }
  for (int t = blockIdx.x * blockDim.x + threadIdx.x; t < NG; t += stride)
    bcnt[t] = 0;
}

// ---------------- CSR build ----------------
// one pass: edge-degree histogram + batch histogram (first NN threads)
__global__ __launch_bounds__(256) void count_all(const int* __restrict__ dst,
                                                 const int* __restrict__ batch,
                                                 int* __restrict__ counts,
                                                 int* __restrict__ bcnt) {
  int e = blockIdx.x * 256 + threadIdx.x;
  atomicAdd(&counts[dst[e]], 1);
  if (e < NN) atomicAdd(&bcnt[batch[e]], 1);
}

__global__ __launch_bounds__(256) void scanA(const int* __restrict__ counts,
                                             int* __restrict__ rp,
                                             int* __restrict__ bsum) {
  __shared__ int sm[256];
  int t = threadIdx.x;
  int g = blockIdx.x * 256 + t;
  int v = counts[g];
  sm[t] = v;
  __syncthreads();
  for (int off = 1; off < 256; off <<= 1) {
    int a = (t >= off) ? sm[t - off] : 0;
    __syncthreads();
    sm[t] += a;
    __syncthreads();
  }
  rp[g] = sm[t] - v;
  if (t == 255) bsum[blockIdx.x] = sm[255];
}

__global__ __launch_bounds__(512) void scanB(int* __restrict__ bsum) {
  __shared__ int sm[512];
  int t = threadIdx.x;
  int v = bsum[t];
  sm[t] = v;
  __syncthreads();
  for (int off = 1; off < 512; off <<= 1) {
    int a = (t >= off) ? sm[t - off] : 0;
    __syncthreads();
    sm[t] += a;
    __syncthreads();
  }
  bsum[t] = sm[t] - v;
}

__global__ __launch_bounds__(256) void scanC(int* __restrict__ rp,
                                             const int* __restrict__ bsum) {
  int g = blockIdx.x * 256 + threadIdx.x;
  rp[g] += bsum[blockIdx.x];
  if (g == 0) rp[NN] = NE;
}

__global__ __launch_bounds__(1024) void scan_batch(const int* __restrict__ bcnt,
                                                   int* __restrict__ bp) {
  __shared__ int sm[1024];
  int t = threadIdx.x;
  int v = bcnt[t];
  sm[t] = v;
  __syncthreads();
  for (int off = 1; off < 1024; off <<= 1) {
    int a = (t >= off) ? sm[t - off] : 0;
    __syncthreads();
    sm[t] += a;
    __syncthreads();
  }
  bp[t] = sm[t] - v;
  if (t == 1023) bp[NG] = NN;
}

// scatter edges into CSR order; pre-permute edge_attr for coalesced conv reads.
__global__ __launch_bounds__(256) void scatter(
    const int* __restrict__ src, const int* __restrict__ dst,
    const float* __restrict__ ea, const int* __restrict__ rp,
    int* __restrict__ fill, int* __restrict__ eperm, int* __restrict__ sp,
    int* __restrict__ dst_p, float* __restrict__ ea_p, int use_eap) {
  int e = blockIdx.x * 256 + threadIdx.x;
  int d = dst[e];
  int p = rp[d] + atomicAdd(&fill[d], 1);
  sp[p] = src[e];
  dst_p[p] = d;
  if (use_eap) {
    const float2* s2 = (const float2*)(ea + (size_t)e * 6);
    float2 a = s2[0], b = s2[1], c = s2[2];
    float2* d2 = (float2*)(ea_p + (size_t)p * 6);
    d2[0] = a; d2[1] = b; d2[2] = c;
  } else {
    eperm[p] = e;
  }
}

// ---------------- node-level GEMMs: P = H@Wd + b1, Q = H@Ws ----------------
// blocks 0..511 compute P, 512..1023 compute Q -> weight base is wave-uniform.
__global__ __launch_bounds__(256, 4) void nodePQ1(
    const float* __restrict__ x, const float* __restrict__ w1,
    const float* __restrict__ b1, float* __restrict__ P, float* __restrict__ Q) {
  int half = blockIdx.x >> 9;
  int n = (blockIdx.x & 511) * 256 + threadIdx.x;
  const float* w = w1 + half * 16 * 64;
  float acc[64];
#pragma unroll
  for (int j = 0; j < 64; j++) acc[j] = half ? 0.0f : b1[j];
  const float4* x4 = (const float4*)(x + (size_t)n * 16);
#pragma unroll
  for (int kk = 0; kk < 4; kk++) {
    float4 v = x4[kk];
    const float* wr = w + (kk * 4) * 64;
#pragma unroll
    for (int j = 0; j < 64; j++) acc[j] = fmaf(v.x, wr[j], acc[j]);
#pragma unroll
    for (int j = 0; j < 64; j++) acc[j] = fmaf(v.y, wr[64 + j], acc[j]);
#pragma unroll
    for (int j = 0; j < 64; j++) acc[j] = fmaf(v.z, wr[128 + j], acc[j]);
#pragma unroll
    for (int j = 0; j < 64; j++) acc[j] = fmaf(v.w, wr[192 + j], acc[j]);
  }
  float4* o = (float4*)((half ? Q : P) + (size_t)n * 64);
#pragma unroll
  for (int j = 0; j < 16; j++)
    o[j] = make_float4(acc[4 * j], acc[4 * j + 1], acc[4 * j + 2], acc[4 * j + 3]);
}

__global__ __launch_bounds__(256, 4) void nodePQ2(
    const unsigned* __restrict__ h1, const float* __restrict__ w1,
    const float* __restrict__ b1, float* __restrict__ P, float* __restrict__ Q) {
  int half = blockIdx.x >> 9;
  int n = (blockIdx.x & 511) * 256 + threadIdx.x;
  const float* w = w1 + half * 64 * 64;
  float acc[64];
#pragma unroll
  for (int j = 0; j < 64; j++) acc[j] = half ? 0.0f : b1[j];
  const uint4* h4 = (const uint4*)(h1 + (size_t)n * 64);
#pragma unroll 4
  for (int kk = 0; kk < 16; kk++) {
    uint4 u = h4[kk];
    float v0 = dec_pos(u.x), v1 = dec_pos(u.y), v2 = dec_pos(u.z), v3 = dec_pos(u.w);
    const float* wr = w + (kk * 4) * 64;
#pragma unroll
    for (int j = 0; j < 64; j++) acc[j] = fmaf(v0, wr[j], acc[j]);
#pragma unroll
    for (int j = 0; j < 64; j++) acc[j] = fmaf(v1, wr[64 + j], acc[j]);
#pragma unroll
    for (int j = 0; j < 64; j++) acc[j] = fmaf(v2, wr[128 + j], acc[j]);
#pragma unroll
    for (int j = 0; j < 64; j++) acc[j] = fmaf(v3, wr[192 + j], acc[j]);
  }
  float4* o = (float4*)((half ? Q : P) + (size_t)n * 64);
#pragma unroll
  for (int j = 0; j < 16; j++)
    o[j] = make_float4(acc[4 * j], acc[4 * j + 1], acc[4 * j + 2], acc[4 * j + 3]);
}

// ---------------- edge kernel: thread per CSR slot ----------------
// Loop-nest inverted vs round 3: out[64] is the only large live array; h is
// produced (and consumed) in 16-wide chunks -> no spill at <=128 VGPR.
template <bool EAP>
__global__ __launch_bounds__(256, 4) void edge_mlp(
    const float* __restrict__ P, const float* __restrict__ Q,
    const float* __restrict__ ea_p, const float* __restrict__ ea,
    const int* __restrict__ eperm, const int* __restrict__ sp,
    const int* __restrict__ dst_p, const int* __restrict__ rp,
    const float* __restrict__ w1c, const float* __restrict__ w2,
    const float* __restrict__ b2, unsigned* __restrict__ hout) {
  int g = blockIdx.x * 256 + threadIdx.x;
  int lane = threadIdx.x & 63;
  int wavebase = g - lane;
  int d = dst_p[g], s = sp[g];
  int seg_lo = rp[d], seg_hi = rp[d + 1];

  float2 ev[3];
  if (EAP) {
    const float2* q = (const float2*)(ea_p + (size_t)g * 6);
    ev[0] = q[0]; ev[1] = q[1]; ev[2] = q[2];
  } else {
    int e = eperm[g];
    const float2* q = (const float2*)(ea + (size_t)e * 6);
    ev[0] = q[0]; ev[1] = q[1]; ev[2] = q[2];
  }

  const float4* Pd = (const float4*)(P + (size_t)d * 64);
  const float4* Qs = (const float4*)(Q + (size_t)s * 64);

  float out[64];
#pragma unroll
  for (int o = 0; o < 64; o++) out[o] = b2[o];

#pragma unroll 1
  for (int jc = 0; jc < 4; ++jc) {  // hidden dim in chunks of 16
    float hj[16];
#pragma unroll
    for (int kk = 0; kk < 4; kk++) {
      float4 a = Pd[jc * 4 + kk];
      float4 b = Qs[jc * 4 + kk];
      hj[4 * kk]     = a.x + b.x;
      hj[4 * kk + 1] = a.y + b.y;
      hj[4 * kk + 2] = a.z + b.z;
      hj[4 * kk + 3] = a.w + b.w;
    }
#pragma unroll
    for (int t = 0; t < 3; t++) {
      const float* wr = w1c + (2 * t) * 64 + jc * 16;
#pragma unroll
      for (int j = 0; j < 16; j++) hj[j] = fmaf(ev[t].x, wr[j], hj[j]);
#pragma unroll
      for (int j = 0; j < 16; j++) hj[j] = fmaf(ev[t].y, wr[64 + j], hj[j]);
    }
#pragma unroll
    for (int j = 0; j < 16; j++) hj[j] = fmaxf(hj[j], 0.0f);

#pragma unroll
    for (int j = 0; j < 16; j++) {
      float hv = hj[j];
      const float* w2r = w2 + (jc * 16 + j) * 64;
#pragma unroll
      for (int o = 0; o < 64; o++) out[o] = fmaf(hv, w2r[o], out[o]);
    }
  }

  // segmented inclusive max-scan over dst-sorted slots, per channel.
  int headlane = seg_lo - wavebase;
  if (headlane < 0) headlane = 0;
  bool tail = (g == seg_hi - 1) || (lane == 63);
  bool whole = (seg_lo >= wavebase) && (seg_hi <= wavebase + 64);
  unsigned* arow = hout + (size_t)d * 64;

#pragma unroll
  for (int o = 0; o < 64; o++) {  // full unroll: out[] must stay in registers
    float v = out[o];
#pragma unroll
    for (int off = 1; off < 64; off <<= 1) {
      float u = __shfl_up(v, off);
      v = (lane - off >= headlane) ? fmaxf(v, u) : v;
    }
    if (tail) {
      if (whole)
        arow[o] = enc_f32(fmaxf(v, 0.0f));
      else
        atomicMax(arow + o, enc_f32(v));
    }
  }
}

// ---------------- fused mean-pool + readout ----------------
__global__ __launch_bounds__(64) void readout(
    const unsigned* __restrict__ h2, const int* __restrict__ bp,
    const float* __restrict__ wr1, const float* __restrict__ br1,
    const float* __restrict__ wr2, const float* __restrict__ br2,
    float* __restrict__ out) {
  int g = blockIdx.x;
  int j = threadIdx.x;
  int lo = bp[g], hi = bp[g + 1];
  float s = 0.0f;
  for (int n = lo; n < hi; ++n) s += dec_pos(h2[(size_t)n * 64 + j]);
  __shared__ float p[64], t[64];
  float c = fmaxf((float)(hi - lo), 1.0f);
  p[j] = s / c;
  __syncthreads();
  float a = br1[j];
#pragma unroll 8
  for (int k = 0; k < 64; k++) a = fmaf(p[k], wr1[k * 64 + j], a);
  t[j] = fmaxf(a, 0.0f);
  __syncthreads();
  float z0 = br2[j], z1 = br2[64 + j];
#pragma unroll 8
  for (int k = 0; k < 64; k++) {
    float tk = t[k];
    z0 = fmaf(tk, wr2[k * 128 + j], z0);
    z1 = fmaf(tk, wr2[k * 128 + 64 + j], z1);
  }
  out[(size_t)g * 128 + j] = z0;
  out[(size_t)g * 128 + 64 + j] = z1;
}

// ---------------- launch ----------------
extern "C" void kernel_launch(void* const* d_in, const int* in_sizes, int n_in,
                              void* d_out, int out_size, void* d_ws, size_t ws_size,
                              hipStream_t stream) {
  const float* x     = (const float*)d_in[0];
  const float* ea    = (const float*)d_in[1];
  const int*   ei    = (const int*)d_in[2];
  const int*   batch = (const int*)d_in[3];
  const float* w11 = (const float*)d_in[4];
  const float* b11 = (const float*)d_in[5];
  const float* w12 = (const float*)d_in[6];
  const float* b12 = (const float*)d_in[7];
  const float* w21 = (const float*)d_in[8];
  const float* b21 = (const float*)d_in[9];
  const float* w22 = (const float*)d_in[10];
  const float* b22 = (const float*)d_in[11];
  const float* wr1 = (const float*)d_in[12];
  const float* br1 = (const float*)d_in[13];
  const float* wr2 = (const float*)d_in[14];
  const float* br2 = (const float*)d_in[15];
  float* out = (float*)d_out;

  const int* src = ei;
  const int* dst = ei + NE;

  char* ws = (char*)d_ws;
  size_t off = 0;
  auto alloc = [&](size_t bytes) {
    char* p = ws + off;
    off = (off + bytes + 255) & ~(size_t)255;
    return p;
  };
  unsigned* h1   = (unsigned*)alloc((size_t)NN * 64 * 4);  // 33.5 MB (encoded)
  unsigned* h2   = (unsigned*)alloc((size_t)NN * 64 * 4);  // 33.5 MB (encoded)
  float*    Pbuf = (float*)alloc((size_t)NN * 64 * 4);     // 33.5 MB
  float*    Qbuf = (float*)alloc((size_t)NN * 64 * 4);     // 33.5 MB
  int*   sp    = (int*)alloc((size_t)NE * 4);
  int*   eperm = (int*)alloc((size_t)NE * 4);
  int*   dst_p = (int*)alloc((size_t)NE * 4);
  int*   rp    = (int*)alloc((size_t)(NN + 1) * 4);
  int*   counts= (int*)alloc((size_t)NN * 4);
  int*   fill  = (int*)alloc((size_t)NN * 4);
  int*   bcnt  = (int*)alloc((size_t)NG * 4);
  int*   bp    = (int*)alloc((size_t)(NG + 1) * 4);
  int*   bsum  = (int*)alloc(512 * 4);
  float* ea_p  = (float*)alloc((size_t)NE * 6 * 4);        // 50.3 MB (optional)
  int use_eap = (off <= ws_size) ? 1 : 0;                  // fallback if ws too small

  init_ws<<<1024, 256, 0, stream>>>((uint4*)h1, (uint4*)h2, counts, fill, bcnt);
  count_all<<<NE / 256, 256, 0, stream>>>(dst, batch, counts, bcnt);
  scanA<<<NN / 256, 256, 0, stream>>>(counts, rp, bsum);
  scanB<<<1, 512, 0, stream>>>(bsum);
  scanC<<<NN / 256, 256, 0, stream>>>(rp, bsum);
  scan_batch<<<1, 1024, 0, stream>>>(bcnt, bp);
  scatter<<<NE / 256, 256, 0, stream>>>(src, dst, ea, rp, fill, eperm, sp,
                                        dst_p, ea_p, use_eap);

  nodePQ1<<<1024, 256, 0, stream>>>(x, w11, b11, Pbuf, Qbuf);
  if (use_eap)
    edge_mlp<true><<<NE / 256, 256, 0, stream>>>(Pbuf, Qbuf, ea_p, ea, eperm, sp,
                                                 dst_p, rp, w11 + 32 * 64, w12, b12, h1);
  else
    edge_mlp<false><<<NE / 256, 256, 0, stream>>>(Pbuf, Qbuf, ea_p, ea, eperm, sp,
                                                  dst_p, rp, w11 + 32 * 64, w12, b12, h1);

  nodePQ2<<<1024, 256, 0, stream>>>(h1, w21, b21, Pbuf, Qbuf);
  if (use_eap)
    edge_mlp<true><<<NE / 256, 256, 0, stream>>>(Pbuf, Qbuf, ea_p, ea, eperm, sp,
                                                 dst_p, rp, w21 + 128 * 64, w22, b22, h2);
  else
    edge_mlp<false><<<NE / 256, 256, 0, stream>>>(Pbuf, Qbuf, ea_p, ea, eperm, sp,
                                                  dst_p, rp, w21 + 128 * 64, w22, b22, h2);

  readout<<<NG, 64, 0, stream>>>(h2, bp, wr1, br1, wr2, br2, out);
}

// Round 5
// 1213.584 us; speedup vs baseline: 9.2232x; 1.0594x over previous
//
#include <hip/hip_runtime.h>
#include <stdint.h>

#define NN 131072
#define NE 2097152
#define NG 1024

// monotone float<->uint encoding: f1 < f2  <=>  enc(f1) < enc(f2) (unsigned).
// h-buffers live in encoded space, initialized to enc(0.0)=0x80000000 so the
// decoded value is relu(segment_max) with empty segments -> 0 (matches ref).
__device__ __forceinline__ unsigned enc_f32(float f) {
  unsigned b = __float_as_uint(f);
  return (b & 0x80000000u) ? ~b : (b | 0x80000000u);
}
__device__ __forceinline__ float dec_pos(unsigned u) {
  return __uint_as_float(u & 0x7fffffffu);
}

// ---------------- init ----------------
__global__ void init_ws(uint4* __restrict__ h1, uint4* __restrict__ h2,
                        int* __restrict__ counts, int* __restrict__ fill,
                        int* __restrict__ bcnt) {
  const int HN4 = NN * 64 / 4;
  uint4 v = make_uint4(0x80000000u, 0x80000000u, 0x80000000u, 0x80000000u);
  int stride = gridDim.x * blockDim.x;
  for (int t = blockIdx.x * blockDim.x + threadIdx.x; t < HN4; t += stride) {
    h1[t] = v;
    h2[t] = v;
  }
  for (int t = blockIdx.x * blockDim.x + threadIdx.x; t < NN; t += stride) {
    counts[t] = 0;
    fill[t] = 0;
  }
  for (int t = blockIdx.x * blockDim.x + threadIdx.x; t < NG; t += stride)
    bcnt[t] = 0;
}

// ---------------- CSR build ----------------
__global__ __launch_bounds__(256) void count_all(const int* __restrict__ dst,
                                                 const int* __restrict__ batch,
                                                 int* __restrict__ counts,
                                                 int* __restrict__ bcnt) {
  int e = blockIdx.x * 256 + threadIdx.x;
  atomicAdd(&counts[dst[e]], 1);
  if (e < NN) atomicAdd(&bcnt[batch[e]], 1);
}

__global__ __launch_bounds__(256) void scanA(const int* __restrict__ counts,
                                             int* __restrict__ rp,
                                             int* __restrict__ bsum) {
  __shared__ int sm[256];
  int t = threadIdx.x;
  int g = blockIdx.x * 256 + t;
  int v = counts[g];
  sm[t] = v;
  __syncthreads();
  for (int off = 1; off < 256; off <<= 1) {
    int a = (t >= off) ? sm[t - off] : 0;
    __syncthreads();
    sm[t] += a;
    __syncthreads();
  }
  rp[g] = sm[t] - v;
  if (t == 255) bsum[blockIdx.x] = sm[255];
}

__global__ __launch_bounds__(512) void scanB(int* __restrict__ bsum) {
  __shared__ int sm[512];
  int t = threadIdx.x;
  int v = bsum[t];
  sm[t] = v;
  __syncthreads();
  for (int off = 1; off < 512; off <<= 1) {
    int a = (t >= off) ? sm[t - off] : 0;
    __syncthreads();
    sm[t] += a;
    __syncthreads();
  }
  bsum[t] = sm[t] - v;
}

__global__ __launch_bounds__(256) void scanC(int* __restrict__ rp,
                                             const int* __restrict__ bsum) {
  int g = blockIdx.x * 256 + threadIdx.x;
  rp[g] += bsum[blockIdx.x];
  if (g == 0) rp[NN] = NE;
}

__global__ __launch_bounds__(1024) void scan_batch(const int* __restrict__ bcnt,
                                                   int* __restrict__ bp) {
  __shared__ int sm[1024];
  int t = threadIdx.x;
  int v = bcnt[t];
  sm[t] = v;
  __syncthreads();
  for (int off = 1; off < 1024; off <<= 1) {
    int a = (t >= off) ? sm[t - off] : 0;
    __syncthreads();
    sm[t] += a;
    __syncthreads();
  }
  bp[t] = sm[t] - v;
  if (t == 1023) bp[NG] = NN;
}

__global__ __launch_bounds__(256) void scatter(
    const int* __restrict__ src, const int* __restrict__ dst,
    const float* __restrict__ ea, const int* __restrict__ rp,
    int* __restrict__ fill, int* __restrict__ eperm, int* __restrict__ sp,
    int* __restrict__ dst_p, float* __restrict__ ea_p, int use_eap) {
  int e = blockIdx.x * 256 + threadIdx.x;
  int d = dst[e];
  int p = rp[d] + atomicAdd(&fill[d], 1);
  sp[p] = src[e];
  dst_p[p] = d;
  if (use_eap) {
    const float2* s2 = (const float2*)(ea + (size_t)e * 6);
    float2 a = s2[0], b = s2[1], c = s2[2];
    float2* d2 = (float2*)(ea_p + (size_t)p * 6);
    d2[0] = a; d2[1] = b; d2[2] = c;
  } else {
    eperm[p] = e;
  }
}

// ---------------- node-level GEMMs: P = H@Wd + b1, Q = H@Ws ----------------
__global__ __launch_bounds__(256, 4) void nodePQ1(
    const float* __restrict__ x, const float* __restrict__ w1,
    const float* __restrict__ b1, float* __restrict__ P, float* __restrict__ Q) {
  int half = blockIdx.x >> 9;
  int n = (blockIdx.x & 511) * 256 + threadIdx.x;
  const float* w = w1 + half * 16 * 64;
  float acc[64];
#pragma unroll
  for (int j = 0; j < 64; j++) acc[j] = half ? 0.0f : b1[j];
  const float4* x4 = (const float4*)(x + (size_t)n * 16);
#pragma unroll
  for (int kk = 0; kk < 4; kk++) {
    float4 v = x4[kk];
    const float* wr = w + (kk * 4) * 64;
#pragma unroll
    for (int j = 0; j < 64; j++) acc[j] = fmaf(v.x, wr[j], acc[j]);
#pragma unroll
    for (int j = 0; j < 64; j++) acc[j] = fmaf(v.y, wr[64 + j], acc[j]);
#pragma unroll
    for (int j = 0; j < 64; j++) acc[j] = fmaf(v.z, wr[128 + j], acc[j]);
#pragma unroll
    for (int j = 0; j < 64; j++) acc[j] = fmaf(v.w, wr[192 + j], acc[j]);
  }
  float4* o = (float4*)((half ? Q : P) + (size_t)n * 64);
#pragma unroll
  for (int j = 0; j < 16; j++)
    o[j] = make_float4(acc[4 * j], acc[4 * j + 1], acc[4 * j + 2], acc[4 * j + 3]);
}

__global__ __launch_bounds__(256, 4) void nodePQ2(
    const unsigned* __restrict__ h1, const float* __restrict__ w1,
    const float* __restrict__ b1, float* __restrict__ P, float* __restrict__ Q) {
  int half = blockIdx.x >> 9;
  int n = (blockIdx.x & 511) * 256 + threadIdx.x;
  const float* w = w1 + half * 64 * 64;
  float acc[64];
#pragma unroll
  for (int j = 0; j < 64; j++) acc[j] = half ? 0.0f : b1[j];
  const uint4* h4 = (const uint4*)(h1 + (size_t)n * 64);
#pragma unroll 4
  for (int kk = 0; kk < 16; kk++) {
    uint4 u = h4[kk];
    float v0 = dec_pos(u.x), v1 = dec_pos(u.y), v2 = dec_pos(u.z), v3 = dec_pos(u.w);
    const float* wr = w + (kk * 4) * 64;
#pragma unroll
    for (int j = 0; j < 64; j++) acc[j] = fmaf(v0, wr[j], acc[j]);
#pragma unroll
    for (int j = 0; j < 64; j++) acc[j] = fmaf(v1, wr[64 + j], acc[j]);
#pragma unroll
    for (int j = 0; j < 64; j++) acc[j] = fmaf(v2, wr[128 + j], acc[j]);
#pragma unroll
    for (int j = 0; j < 64; j++) acc[j] = fmaf(v3, wr[192 + j], acc[j]);
  }
  float4* o = (float4*)((half ? Q : P) + (size_t)n * 64);
#pragma unroll
  for (int j = 0; j < 16; j++)
    o[j] = make_float4(acc[4 * j], acc[4 * j + 1], acc[4 * j + 2], acc[4 * j + 3]);
}

// ---------------- edge kernel: thread per CSR slot ----------------
// Output channels processed in halves of 32 (out[32] live -> ~80 VGPR, no
// spill). Reduction over edges via per-wave LDS transpose + uniform serial
// segmented max (lane = channel). No shfl-scan, no 64-wide register arrays.
template <bool EAP>
__global__ __launch_bounds__(256, 4) void edge_mlp(
    const float* __restrict__ P, const float* __restrict__ Q,
    const float* __restrict__ ea_p, const float* __restrict__ ea,
    const int* __restrict__ eperm, const int* __restrict__ sp,
    const int* __restrict__ dst_p, const int* __restrict__ rp,
    const float* __restrict__ w1c, const float* __restrict__ w2,
    const float* __restrict__ b2, unsigned* __restrict__ hout) {
  __shared__ float tile[4][64 * 32];  // per-wave 8 KB transpose tile
  __shared__ int dar[4][64];          // packed: sign bit = whole-in-wave, low = d

  int tid = threadIdx.x;
  int wv = tid >> 6, lane = tid & 63;
  int g = blockIdx.x * 256 + tid;  // CSR slot
  int wavebase = g - lane;
  int d = dst_p[g], s = sp[g];
  int seg_lo = rp[d], seg_hi = rp[d + 1];
  bool whole = (seg_lo >= wavebase) && (seg_hi <= wavebase + 64);
  dar[wv][lane] = d | (whole ? (int)0x80000000 : 0);

  float2 ev[3];
  if (EAP) {
    const float2* q = (const float2*)(ea_p + (size_t)g * 6);
    ev[0] = q[0]; ev[1] = q[1]; ev[2] = q[2];
  } else {
    int e = eperm[g];
    const float2* q = (const float2*)(ea + (size_t)e * 6);
    ev[0] = q[0]; ev[1] = q[1]; ev[2] = q[2];
  }

  const float4* Pd = (const float4*)(P + (size_t)d * 64);
  const float4* Qs = (const float4*)(Q + (size_t)s * 64);
  float* mytile = tile[wv];
  int swz = (lane & 7) << 2;  // XOR swizzle of dword-in-row (keeps 16B align)

#pragma unroll 1
  for (int half = 0; half < 2; ++half) {
    float out[32];
#pragma unroll
    for (int o = 0; o < 32; o++) out[o] = b2[half * 32 + o];

#pragma unroll 1
    for (int jc = 0; jc < 4; ++jc) {  // hidden dim in chunks of 16 (recomputed per half)
      float hj[16];
#pragma unroll
      for (int kk = 0; kk < 4; kk++) {
        float4 a = Pd[jc * 4 + kk];
        float4 b = Qs[jc * 4 + kk];
        hj[4 * kk]     = a.x + b.x;
        hj[4 * kk + 1] = a.y + b.y;
        hj[4 * kk + 2] = a.z + b.z;
        hj[4 * kk + 3] = a.w + b.w;
      }
#pragma unroll
      for (int t = 0; t < 3; t++) {
        const float* wr = w1c + (2 * t) * 64 + jc * 16;
#pragma unroll
        for (int j = 0; j < 16; j++) hj[j] = fmaf(ev[t].x, wr[j], hj[j]);
#pragma unroll
        for (int j = 0; j < 16; j++) hj[j] = fmaf(ev[t].y, wr[64 + j], hj[j]);
      }
#pragma unroll
      for (int j = 0; j < 16; j++) hj[j] = fmaxf(hj[j], 0.0f);

#pragma unroll
      for (int j = 0; j < 16; j++) {
        float hv = hj[j];
        const float* w2r = w2 + (jc * 16 + j) * 64 + half * 32;
#pragma unroll
        for (int o = 0; o < 32; o++) out[o] = fmaf(hv, w2r[o], out[o]);
      }
    }

    // write my edge's 32 outputs to the wave tile (swizzled columns)
#pragma unroll
    for (int k = 0; k < 8; ++k) {
      int cdst = (4 * k) ^ swz;
      *(float4*)&mytile[lane * 32 + cdst] =
          make_float4(out[4 * k], out[4 * k + 1], out[4 * k + 2], out[4 * k + 3]);
    }
    // wave-local fence: this wave's DS writes complete before reads
    asm volatile("s_waitcnt lgkmcnt(0)" ::: "memory");

    // lanes 0..31: lane = channel; serial uniform scan over the 64 edges
    if (lane < 32) {
      float mx = 0.0f;
      int cur = dar[wv][0];
#pragma unroll 8
      for (int e = 0; e < 64; ++e) {
        float v = mytile[e * 32 + (lane ^ ((e & 7) << 2))];
        mx = fmaxf(mx, v);
        int nxt = (e < 63) ? dar[wv][e + 1] : 0x7fffffff;
        if (cur != nxt) {  // uniform across lanes: segment boundary -> flush
          unsigned encv = enc_f32(mx);
          unsigned* addr =
              hout + (size_t)(cur & 0x7fffffff) * 64 + half * 32 + lane;
          if (cur < 0) *addr = encv;       // whole-in-wave: plain store
          else atomicMax(addr, encv);      // crosses wave boundary
          mx = 0.0f;
        }
        cur = nxt;
      }
    }
    // WAR fence before next half overwrites the tile
    asm volatile("s_waitcnt lgkmcnt(0)" ::: "memory");
  }
}

// ---------------- fused mean-pool + readout: 4-wave block per graph ----------------
__global__ __launch_bounds__(256) void readout(
    const unsigned* __restrict__ h2, const int* __restrict__ bp,
    const float* __restrict__ wr1, const float* __restrict__ br1,
    const float* __restrict__ wr2, const float* __restrict__ br2,
    float* __restrict__ out) {
  int g = blockIdx.x;
  int tid = threadIdx.x;
  int wv = tid >> 6, lane = tid & 63;
  int lo = bp[g], hi = bp[g + 1];
  float s = 0.0f;
  for (int n = lo + wv; n < hi; n += 4) s += dec_pos(h2[(size_t)n * 64 + lane]);
  __shared__ float part[4][64];
  __shared__ float p[64], t[64];
  part[wv][lane] = s;
  __syncthreads();
  if (tid < 64) {
    float c = fmaxf((float)(hi - lo), 1.0f);
    p[tid] = (part[0][tid] + part[1][tid] + part[2][tid] + part[3][tid]) / c;
  }
  __syncthreads();
  if (tid < 64) {
    float a = br1[tid];
#pragma unroll 8
    for (int k = 0; k < 64; k++) a = fmaf(p[k], wr1[k * 64 + tid], a);
    t[tid] = fmaxf(a, 0.0f);
  }
  __syncthreads();
  if (tid < 64) {
    float z0 = br2[tid], z1 = br2[64 + tid];
#pragma unroll 8
    for (int k = 0; k < 64; k++) {
      float tk = t[k];
      z0 = fmaf(tk, wr2[k * 128 + tid], z0);
      z1 = fmaf(tk, wr2[k * 128 + 64 + tid], z1);
    }
    out[(size_t)g * 128 + tid] = z0;
    out[(size_t)g * 128 + 64 + tid] = z1;
  }
}

// ---------------- launch ----------------
extern "C" void kernel_launch(void* const* d_in, const int* in_sizes, int n_in,
                              void* d_out, int out_size, void* d_ws, size_t ws_size,
                              hipStream_t stream) {
  const float* x     = (const float*)d_in[0];
  const float* ea    = (const float*)d_in[1];
  const int*   ei    = (const int*)d_in[2];
  const int*   batch = (const int*)d_in[3];
  const float* w11 = (const float*)d_in[4];
  const float* b11 = (const float*)d_in[5];
  const float* w12 = (const float*)d_in[6];
  const float* b12 = (const float*)d_in[7];
  const float* w21 = (const float*)d_in[8];
  const float* b21 = (const float*)d_in[9];
  const float* w22 = (const float*)d_in[10];
  const float* b22 = (const float*)d_in[11];
  const float* wr1 = (const float*)d_in[12];
  const float* br1 = (const float*)d_in[13];
  const float* wr2 = (const float*)d_in[14];
  const float* br2 = (const float*)d_in[15];
  float* out = (float*)d_out;

  const int* src = ei;
  const int* dst = ei + NE;

  char* ws = (char*)d_ws;
  size_t off = 0;
  auto alloc = [&](size_t bytes) {
    char* p = ws + off;
    off = (off + bytes + 255) & ~(size_t)255;
    return p;
  };
  unsigned* h1   = (unsigned*)alloc((size_t)NN * 64 * 4);
  unsigned* h2   = (unsigned*)alloc((size_t)NN * 64 * 4);
  float*    Pbuf = (float*)alloc((size_t)NN * 64 * 4);
  float*    Qbuf = (float*)alloc((size_t)NN * 64 * 4);
  int*   sp    = (int*)alloc((size_t)NE * 4);
  int*   eperm = (int*)alloc((size_t)NE * 4);
  int*   dst_p = (int*)alloc((size_t)NE * 4);
  int*   rp    = (int*)alloc((size_t)(NN + 1) * 4);
  int*   counts= (int*)alloc((size_t)NN * 4);
  int*   fill  = (int*)alloc((size_t)NN * 4);
  int*   bcnt  = (int*)alloc((size_t)NG * 4);
  int*   bp    = (int*)alloc((size_t)(NG + 1) * 4);
  int*   bsum  = (int*)alloc(512 * 4);
  float* ea_p  = (float*)alloc((size_t)NE * 6 * 4);
  int use_eap = (off <= ws_size) ? 1 : 0;

  init_ws<<<1024, 256, 0, stream>>>((uint4*)h1, (uint4*)h2, counts, fill, bcnt);
  count_all<<<NE / 256, 256, 0, stream>>>(dst, batch, counts, bcnt);
  scanA<<<NN / 256, 256, 0, stream>>>(counts, rp, bsum);
  scanB<<<1, 512, 0, stream>>>(bsum);
  scanC<<<NN / 256, 256, 0, stream>>>(rp, bsum);
  scan_batch<<<1, 1024, 0, stream>>>(bcnt, bp);
  scatter<<<NE / 256, 256, 0, stream>>>(src, dst, ea, rp, fill, eperm, sp,
                                        dst_p, ea_p, use_eap);

  nodePQ1<<<1024, 256, 0, stream>>>(x, w11, b11, Pbuf, Qbuf);
  if (use_eap)
    edge_mlp<true><<<NE / 256, 256, 0, stream>>>(Pbuf, Qbuf, ea_p, ea, eperm, sp,
                                                 dst_p, rp, w11 + 32 * 64, w12, b12, h1);
  else
    edge_mlp<false><<<NE / 256, 256, 0, stream>>>(Pbuf, Qbuf, ea_p, ea, eperm, sp,
                                                  dst_p, rp, w11 + 32 * 64, w12, b12, h1);

  nodePQ2<<<1024, 256, 0, stream>>>(h1, w21, b21, Pbuf, Qbuf);
  if (use_eap)
    edge_mlp<true><<<NE / 256, 256, 0, stream>>>(Pbuf, Qbuf, ea_p, ea, eperm, sp,
                                                 dst_p, rp, w21 + 128 * 64, w22, b22, h2);
  else
    edge_mlp<false><<<NE / 256, 256, 0, stream>>>(Pbuf, Qbuf, ea_p, ea, eperm, sp,
                                                  dst_p, rp, w21 + 128 * 64, w22, b22, h2);

  readout<<<NG, 256, 0, stream>>>(h2, bp, wr1, br1, wr2, br2, out);
}